// Round 1
// baseline (37.851 us; speedup 1.0000x reference)
//
#include <hip/hip_runtime.h>
#include <math.h>

// Shapes fixed by the problem: B=2, S=512, E=256, H=8, D=32, 33 relation buckets.
namespace {
constexpr int E_  = 256;
constexpr int H_  = 8;
constexpr int D_  = 32;
constexpr int S_  = 512;
constexpr int B_  = 2;
constexpr int NR_ = 33;
constexpr int ROWS_ = B_ * S_;          // 1024
constexpr int MATELEMS_ = ROWS_ * E_;   // 262144 floats per projection
}

// ---------------------------------------------------------------------------
// Projection GEMM: C[m][n] = sum_k A[m][k] * W[n][k]   (torch Linear: x @ W.T)
// BM=32, BN=64, BK=32, 256 threads, 2x4 micro-tile per thread.
// grid = (ROWS/32, E/64, 3); z selects {query,W_Q}->q / {key,W_K}->k / {value,W_V}->v
// ---------------------------------------------------------------------------
__global__ __launch_bounds__(256) void proj_kernel(
    const float* __restrict__ in_q, const float* __restrict__ in_k,
    const float* __restrict__ in_v,
    const float* __restrict__ WQ, const float* __restrict__ WK,
    const float* __restrict__ WV,
    float* __restrict__ ws)
{
    constexpr int BM = 32, BN = 64, BK = 32;
    __shared__ float As[BM][BK + 1];   // +1 pad: breaks power-of-2 bank stride
    __shared__ float Ws[BN][BK + 1];

    const int t  = threadIdx.x;
    const int m0 = blockIdx.x * BM;
    const int n0 = blockIdx.y * BN;
    const int z  = blockIdx.z;

    const float* A = (z == 0) ? in_q : (z == 1) ? in_k : in_v;
    const float* W = (z == 0) ? WQ   : (z == 1) ? WK   : WV;
    float* C = ws + (size_t)z * MATELEMS_;

    // load indices
    const int a_row = t >> 3;            // 32 rows, 8 threads/row
    const int a_c   = (t & 7) * 4;       // float4 per thread
    const int w_row = t >> 2;            // 64 rows, 4 threads/row
    const int w_c   = (t & 3) * 8;       // 2x float4 per thread

    // compute indices: 16 row-groups x 16 col-groups
    const int tr = t >> 4;               // [0,16) -> rows 2*tr, 2*tr+1
    const int tc = t & 15;               // [0,16) -> cols 4*tc .. 4*tc+3

    float acc[2][4] = {{0.f,0.f,0.f,0.f},{0.f,0.f,0.f,0.f}};

    for (int kk0 = 0; kk0 < E_; kk0 += BK) {
        const float4 av = *reinterpret_cast<const float4*>(
            &A[(size_t)(m0 + a_row) * E_ + kk0 + a_c]);
        As[a_row][a_c + 0] = av.x; As[a_row][a_c + 1] = av.y;
        As[a_row][a_c + 2] = av.z; As[a_row][a_c + 3] = av.w;

        const float4 wv0 = *reinterpret_cast<const float4*>(
            &W[(size_t)(n0 + w_row) * E_ + kk0 + w_c]);
        const float4 wv1 = *reinterpret_cast<const float4*>(
            &W[(size_t)(n0 + w_row) * E_ + kk0 + w_c + 4]);
        Ws[w_row][w_c + 0] = wv0.x; Ws[w_row][w_c + 1] = wv0.y;
        Ws[w_row][w_c + 2] = wv0.z; Ws[w_row][w_c + 3] = wv0.w;
        Ws[w_row][w_c + 4] = wv1.x; Ws[w_row][w_c + 5] = wv1.y;
        Ws[w_row][w_c + 6] = wv1.z; Ws[w_row][w_c + 7] = wv1.w;

        __syncthreads();

        #pragma unroll
        for (int kk = 0; kk < BK; ++kk) {
            const float a0 = As[2 * tr + 0][kk];
            const float a1 = As[2 * tr + 1][kk];
            const float b0 = Ws[4 * tc + 0][kk];
            const float b1 = Ws[4 * tc + 1][kk];
            const float b2 = Ws[4 * tc + 2][kk];
            const float b3 = Ws[4 * tc + 3][kk];
            acc[0][0] += a0 * b0; acc[0][1] += a0 * b1;
            acc[0][2] += a0 * b2; acc[0][3] += a0 * b3;
            acc[1][0] += a1 * b0; acc[1][1] += a1 * b1;
            acc[1][2] += a1 * b2; acc[1][3] += a1 * b3;
        }
        __syncthreads();
    }

    #pragma unroll
    for (int r = 0; r < 2; ++r) {
        float4 o;
        o.x = acc[r][0]; o.y = acc[r][1]; o.z = acc[r][2]; o.w = acc[r][3];
        *reinterpret_cast<float4*>(
            &C[(size_t)(m0 + 2 * tr + r) * E_ + n0 + 4 * tc]) = o;
    }
}

// ---------------------------------------------------------------------------
// Fused attention: one block per (b,i) row. Exploits the 33-bucket structure:
// softmax over relation buckets (exact reassociation of the reference), then
// z = v + sum_r w_r * rel_emb[r].
// ---------------------------------------------------------------------------
__global__ __launch_bounds__(256) void attn_kernel(
    const float* __restrict__ ws,          // q | k | v, each ROWS_*E_
    const int*   __restrict__ relations,   // [B,S,S] int32
    const float* __restrict__ rel_emb,     // [33, E]
    float* __restrict__ out)               // [B,S,E]
{
    __shared__ float q_s[E_];
    __shared__ float k_s[E_];
    __shared__ float v_s[E_];
    __shared__ float qr_s[H_][NR_];
    __shared__ float qkd_s[H_];
    __shared__ int   cnt_s[NR_];

    const int t   = threadIdx.x;           // 256 threads
    const int row = blockIdx.x;            // b*S + i
    const float* q = ws;
    const float* k = ws + MATELEMS_;
    const float* v = ws + 2 * MATELEMS_;

    q_s[t] = q[(size_t)row * E_ + t];
    k_s[t] = k[(size_t)row * E_ + t];
    v_s[t] = v[(size_t)row * E_ + t];
    if (t < NR_) cnt_s[t] = 0;
    __syncthreads();

    const int h = t >> 5;                  // head
    const int d = t & 31;                  // dim within head

    // qk_diag[h] = q_i . k_i  (per head) — 32-lane group reduction
    float prod = q_s[t] * k_s[t];
    #pragma unroll
    for (int m = 16; m >= 1; m >>= 1) prod += __shfl_xor(prod, m);
    if (d == 0) qkd_s[h] = prod;

    // histogram of relations[b,i,:] over 33 buckets
    {
        const int r0 = relations[(size_t)row * S_ + t];
        const int r1 = relations[(size_t)row * S_ + t + 256];
        atomicAdd(&cnt_s[r0], 1);
        atomicAdd(&cnt_s[r1], 1);
    }

    // qr[h][r] = q_i[hD:(h+1)D] . rel_emb[r, hD:(h+1)D]  (264 tasks)
    for (int tt = t; tt < H_ * NR_; tt += 256) {
        const int hh = tt / NR_;
        const int r  = tt % NR_;
        const float* emb = rel_emb + (size_t)r * E_ + hh * D_;
        const float* qq  = q_s + hh * D_;
        float s = 0.f;
        #pragma unroll
        for (int dd = 0; dd < D_; ++dd) s += qq[dd] * emb[dd];
        qr_s[hh][r] = s;
    }
    __syncthreads();

    // bucket softmax + output
    const float scale = 0.17677669529663687f;   // 1/sqrt(32)
    const float qkd = qkd_s[h];
    float mmax = -1e30f;
    #pragma unroll
    for (int r = 0; r < NR_; ++r)
        mmax = fmaxf(mmax, qkd + qr_s[h][r]);
    mmax *= scale;

    float denom = 0.f, acc = 0.f;
    #pragma unroll
    for (int r = 0; r < NR_; ++r) {
        const int c = cnt_s[r];
        if (c) {
            const float e = (float)c * __expf((qkd + qr_s[h][r]) * scale - mmax);
            denom += e;
            acc   += e * rel_emb[(size_t)r * E_ + t];   // h*D + d == t
        }
    }
    out[(size_t)row * E_ + t] = v_s[t] + acc / denom;
}

extern "C" void kernel_launch(void* const* d_in, const int* in_sizes, int n_in,
                              void* d_out, int out_size, void* d_ws, size_t ws_size,
                              hipStream_t stream) {
    const float* query     = (const float*)d_in[0];
    const float* key       = (const float*)d_in[1];
    const float* value     = (const float*)d_in[2];
    const int*   relations = (const int*)  d_in[3];   // int inputs arrive as int32
    const float* W_Q       = (const float*)d_in[4];
    const float* W_K       = (const float*)d_in[5];
    const float* W_V       = (const float*)d_in[6];
    const float* rel_emb   = (const float*)d_in[7];
    float* out = (float*)d_out;
    float* ws  = (float*)d_ws;   // q | k | v projections, 3 * 1 MB

    // Projections q,k,v
    dim3 pgrid(ROWS_ / 32, E_ / 64, 3);
    proj_kernel<<<pgrid, 256, 0, stream>>>(query, key, value, W_Q, W_K, W_V, ws);

    // Fused bucketed attention
    attn_kernel<<<ROWS_, 256, 0, stream>>>(ws, relations, rel_emb, out);
}

// Round 2
// 28.043 us; speedup vs baseline: 1.3498x; 1.3498x over previous
//
#include <hip/hip_runtime.h>
#include <math.h>

// Shapes fixed by the problem: B=2, S=512, E=256, H=8, D=32, 33 relation buckets.
namespace {
constexpr int E_  = 256;
constexpr int H_  = 8;
constexpr int D_  = 32;
constexpr int S_  = 512;
constexpr int B_  = 2;
constexpr int NR_ = 33;
constexpr int ROWS_ = B_ * S_;          // 1024
constexpr int MATELEMS_ = ROWS_ * E_;   // 262144 floats per projection
}

// ---------------------------------------------------------------------------
// Projection GEMM: C[m][n] = sum_k A[m][k] * W[n][k]   (torch Linear: x @ W.T)
// BM=64, BN=64, BK=32, 256 threads, 4x4 micro-tile -> 16 FMA per 2 ds_read_b128
// (FMA-bound). Transposed LDS [BK][BM+4]: fragment reads are contiguous float4,
// 16B-aligned (stride 272B). Register prefetch of next K-tile hides global lat.
// grid = (16, 4, 3); z selects {query,W_Q} / {key,W_K} / {value,W_V}.
// ---------------------------------------------------------------------------
__global__ __launch_bounds__(256) void proj_kernel(
    const float* __restrict__ in_q, const float* __restrict__ in_k,
    const float* __restrict__ in_v,
    const float* __restrict__ WQ, const float* __restrict__ WK,
    const float* __restrict__ WV,
    float* __restrict__ ws)
{
    constexpr int BM = 64, BN = 64, BK = 32;
    constexpr int LDA = BM + 4;   // pad 4: keeps 16B alignment, spreads write banks
    __shared__ __align__(16) float As[BK][LDA];   // [kk][m]
    __shared__ __align__(16) float Bs[BK][LDA];   // [kk][n]

    const int t  = threadIdx.x;
    const int m0 = blockIdx.x * BM;
    const int n0 = blockIdx.y * BN;
    const int z  = blockIdx.z;

    const float* A = (z == 0) ? in_q : (z == 1) ? in_k : in_v;
    const float* W = (z == 0) ? WQ   : (z == 1) ? WK   : WV;
    float* C = ws + (size_t)z * MATELEMS_;

    // staging: 2 tasks/thread; task = t + 256*i -> row r = task>>3, col-group c = task&7
    const int r0s = (t >> 3);          // task i=0 row (0..31)
    const int r1s = r0s + 32;          // task i=1 row (32..63)
    const int cs  = (t & 7) * 4;       // col within K-tile (0,4,..,28)

    // compute indices: 4x4 micro-tile
    const int tr = (t >> 4) * 4;       // rows tr..tr+3   (0..60)
    const int tc = (t & 15) * 4;       // cols tc..tc+3   (0..60)

    float acc[4][4];
    #pragma unroll
    for (int i = 0; i < 4; ++i)
        #pragma unroll
        for (int j = 0; j < 4; ++j) acc[i][j] = 0.f;

    // prefetch tile 0 into registers
    float4 a_pre0 = *reinterpret_cast<const float4*>(&A[(size_t)(m0 + r0s) * E_ + cs]);
    float4 a_pre1 = *reinterpret_cast<const float4*>(&A[(size_t)(m0 + r1s) * E_ + cs]);
    float4 b_pre0 = *reinterpret_cast<const float4*>(&W[(size_t)(n0 + r0s) * E_ + cs]);
    float4 b_pre1 = *reinterpret_cast<const float4*>(&W[(size_t)(n0 + r1s) * E_ + cs]);

    for (int kt = 0; kt < E_ / BK; ++kt) {
        // write staged registers to (transposed) LDS
        As[cs + 0][r0s] = a_pre0.x; As[cs + 1][r0s] = a_pre0.y;
        As[cs + 2][r0s] = a_pre0.z; As[cs + 3][r0s] = a_pre0.w;
        As[cs + 0][r1s] = a_pre1.x; As[cs + 1][r1s] = a_pre1.y;
        As[cs + 2][r1s] = a_pre1.z; As[cs + 3][r1s] = a_pre1.w;
        Bs[cs + 0][r0s] = b_pre0.x; Bs[cs + 1][r0s] = b_pre0.y;
        Bs[cs + 2][r0s] = b_pre0.z; Bs[cs + 3][r0s] = b_pre0.w;
        Bs[cs + 0][r1s] = b_pre1.x; Bs[cs + 1][r1s] = b_pre1.y;
        Bs[cs + 2][r1s] = b_pre1.z; Bs[cs + 3][r1s] = b_pre1.w;
        __syncthreads();

        // prefetch next tile (overlaps with compute below)
        if (kt < E_ / BK - 1) {
            const int k0 = (kt + 1) * BK + cs;
            a_pre0 = *reinterpret_cast<const float4*>(&A[(size_t)(m0 + r0s) * E_ + k0]);
            a_pre1 = *reinterpret_cast<const float4*>(&A[(size_t)(m0 + r1s) * E_ + k0]);
            b_pre0 = *reinterpret_cast<const float4*>(&W[(size_t)(n0 + r0s) * E_ + k0]);
            b_pre1 = *reinterpret_cast<const float4*>(&W[(size_t)(n0 + r1s) * E_ + k0]);
        }

        #pragma unroll
        for (int kk = 0; kk < BK; ++kk) {
            const float4 a = *reinterpret_cast<const float4*>(&As[kk][tr]);
            const float4 b = *reinterpret_cast<const float4*>(&Bs[kk][tc]);
            acc[0][0] += a.x * b.x; acc[0][1] += a.x * b.y; acc[0][2] += a.x * b.z; acc[0][3] += a.x * b.w;
            acc[1][0] += a.y * b.x; acc[1][1] += a.y * b.y; acc[1][2] += a.y * b.z; acc[1][3] += a.y * b.w;
            acc[2][0] += a.z * b.x; acc[2][1] += a.z * b.y; acc[2][2] += a.z * b.z; acc[2][3] += a.z * b.w;
            acc[3][0] += a.w * b.x; acc[3][1] += a.w * b.y; acc[3][2] += a.w * b.z; acc[3][3] += a.w * b.w;
        }
        __syncthreads();
    }

    #pragma unroll
    for (int i = 0; i < 4; ++i) {
        float4 o;
        o.x = acc[i][0]; o.y = acc[i][1]; o.z = acc[i][2]; o.w = acc[i][3];
        *reinterpret_cast<float4*>(&C[(size_t)(m0 + tr + i) * E_ + n0 + tc]) = o;
    }
}

// ---------------------------------------------------------------------------
// Fused attention: one block per (b,i) row. 33-bucket softmax (exact
// reassociation of the reference). rel_emb staged in LDS (33.8 KB), qr dots
// vectorized float4, k/v read straight from global.
// ---------------------------------------------------------------------------
__global__ __launch_bounds__(256) void attn_kernel(
    const float* __restrict__ ws,          // q | k | v, each ROWS_*E_
    const int*   __restrict__ relations,   // [B,S,S] int32
    const float* __restrict__ rel_emb,     // [33, E]
    float* __restrict__ out)               // [B,S,E]
{
    __shared__ __align__(16) float emb_s[NR_ * E_];   // 33*256 floats = 33 KB
    __shared__ __align__(16) float q_s[E_];
    __shared__ float qr_s[H_][NR_];
    __shared__ float qkd_s[H_];
    __shared__ int   cnt_s[NR_];

    const int t   = threadIdx.x;           // 256 threads
    const int row = blockIdx.x;            // b*S + i
    const float* q = ws;
    const float* k = ws + MATELEMS_;
    const float* v = ws + 2 * MATELEMS_;

    // stage rel_emb (2112 float4 / 256 threads)
    {
        const float4* src = reinterpret_cast<const float4*>(rel_emb);
        float4* dst = reinterpret_cast<float4*>(emb_s);
        #pragma unroll
        for (int i = t; i < NR_ * E_ / 4; i += 256) dst[i] = src[i];
    }
    q_s[t] = q[(size_t)row * E_ + t];
    if (t < NR_) cnt_s[t] = 0;
    const float kv = k[(size_t)row * E_ + t];
    __syncthreads();

    const int h = t >> 5;                  // head
    const int d = t & 31;                  // dim within head

    // qk_diag[h] = q_i . k_i (per head) — 32-lane group reduction
    float prod = q_s[t] * kv;
    #pragma unroll
    for (int m = 16; m >= 1; m >>= 1) prod += __shfl_xor(prod, m);
    if (d == 0) qkd_s[h] = prod;

    // histogram of relations[b,i,:]
    {
        const int r0 = relations[(size_t)row * S_ + t];
        const int r1 = relations[(size_t)row * S_ + t + 256];
        atomicAdd(&cnt_s[r0], 1);
        atomicAdd(&cnt_s[r1], 1);
    }

    // qr[h][r] = q_i[hD:(h+1)D] . rel_emb[r, hD:(h+1)D]   (264 tasks, float4)
    for (int tt = t; tt < H_ * NR_; tt += 256) {
        const int hh = tt / NR_;
        const int r  = tt - hh * NR_;
        const float4* e4 = reinterpret_cast<const float4*>(&emb_s[r * E_ + hh * D_]);
        const float4* q4 = reinterpret_cast<const float4*>(&q_s[hh * D_]);
        float s = 0.f;
        #pragma unroll
        for (int dd = 0; dd < D_ / 4; ++dd) {
            const float4 qv = q4[dd];
            const float4 ev = e4[dd];
            s += qv.x * ev.x + qv.y * ev.y + qv.z * ev.z + qv.w * ev.w;
        }
        qr_s[hh][r] = s;
    }
    __syncthreads();

    // bucket softmax + output
    const float scale = 0.17677669529663687f;   // 1/sqrt(32)
    const float qkd = qkd_s[h];
    float mmax = -1e30f;
    #pragma unroll
    for (int r = 0; r < NR_; ++r)
        mmax = fmaxf(mmax, qkd + qr_s[h][r]);
    mmax *= scale;

    float denom = 0.f, acc = 0.f;
    #pragma unroll
    for (int r = 0; r < NR_; ++r) {
        const float e = (float)cnt_s[r] * __expf((qkd + qr_s[h][r]) * scale - mmax);
        denom += e;
        acc   += e * emb_s[r * E_ + t];   // h*D + d == t
    }
    out[(size_t)row * E_ + t] = v[(size_t)row * E_ + t] + acc / denom;
}

extern "C" void kernel_launch(void* const* d_in, const int* in_sizes, int n_in,
                              void* d_out, int out_size, void* d_ws, size_t ws_size,
                              hipStream_t stream) {
    const float* query     = (const float*)d_in[0];
    const float* key       = (const float*)d_in[1];
    const float* value     = (const float*)d_in[2];
    const int*   relations = (const int*)  d_in[3];
    const float* W_Q       = (const float*)d_in[4];
    const float* W_K       = (const float*)d_in[5];
    const float* W_V       = (const float*)d_in[6];
    const float* rel_emb   = (const float*)d_in[7];
    float* out = (float*)d_out;
    float* ws  = (float*)d_ws;   // q | k | v projections, 3 MB

    dim3 pgrid(ROWS_ / 64, E_ / 64, 3);
    proj_kernel<<<pgrid, 256, 0, stream>>>(query, key, value, W_Q, W_K, W_V, ws);
    attn_kernel<<<ROWS_, 256, 0, stream>>>(ws, relations, rel_emb, out);
}

// Round 3
// 19.021 us; speedup vs baseline: 1.9900x; 1.4743x over previous
//
#include <hip/hip_runtime.h>
#include <math.h>

// Shapes fixed by the problem: B=2, S=512, E=256, H=8, D=32, 33 relation buckets.
namespace {
constexpr int E_  = 256;
constexpr int H_  = 8;
constexpr int D_  = 32;
constexpr int S_  = 512;
constexpr int B_  = 2;
constexpr int NR_ = 33;
constexpr int ROWS_ = B_ * S_;          // 1024
constexpr int MATELEMS_ = ROWS_ * E_;   // 262144 floats per projection
}

using f32x4 = __attribute__((ext_vector_type(4))) float;
using s16x8 = __attribute__((ext_vector_type(8))) short;

// fp32 -> bf16 round-to-nearest-even, packed pair into one u32
__device__ inline unsigned pk_bf16(float a, float b) {
    unsigned ua = __float_as_uint(a); ua += 0x7FFFu + ((ua >> 16) & 1u);
    unsigned ub = __float_as_uint(b); ub += 0x7FFFu + ((ub >> 16) & 1u);
    return (ua >> 16) | (ub & 0xFFFF0000u);
}

// XOR-swizzled byte offset within a [64 rows][512 B] bf16 tile (T2, G4):
// spreads the 16-row fragment reads across bank groups -> b128 floor.
__device__ inline int swz(int row, int kbyte) {
    return (row << 9) + (kbyte ^ ((row & 7) << 4));
}

// ---------------------------------------------------------------------------
// Projection GEMM via bf16 MFMA: C[m][n] = sum_k A[m][k] * W[n][k].
// 64x64 tile, whole K=256 staged once (A,B bf16 = 64 KB LDS), 4 waves,
// each wave one 32x32 quadrant = 2x2 frags of mfma_f32_16x16x32_bf16.
// grid = (16, 4, 3); z selects {query,W_Q} / {key,W_K} / {value,W_V}.
// ---------------------------------------------------------------------------
__global__ __launch_bounds__(256) void proj_kernel(
    const float* __restrict__ in_q, const float* __restrict__ in_k,
    const float* __restrict__ in_v,
    const float* __restrict__ WQ, const float* __restrict__ WK,
    const float* __restrict__ WV,
    float* __restrict__ ws)
{
    __shared__ __align__(16) char lds[65536];   // A tile 32 KB | B tile 32 KB
    char* aB = lds;
    char* bB = lds + 32768;

    const int t  = threadIdx.x;
    const int m0 = blockIdx.x * 64;
    const int n0 = blockIdx.y * 64;
    const int z  = blockIdx.z;

    const float* A = (z == 0) ? in_q : (z == 1) ? in_k : in_v;
    const float* W = (z == 0) ? WQ   : (z == 1) ? WK   : WV;
    float* C = ws + (size_t)z * MATELEMS_;

    // ---- stage: 64 rows x 64 float4 per matrix, 16 tasks/thread, coalesced
    #pragma unroll
    for (int i = t; i < 64 * 64; i += 256) {
        const int row = i >> 6;
        const int c4  = i & 63;
        const float4 av = *reinterpret_cast<const float4*>(
            &A[(size_t)(m0 + row) * E_ + c4 * 4]);
        *reinterpret_cast<uint2*>(aB + swz(row, c4 * 8)) =
            make_uint2(pk_bf16(av.x, av.y), pk_bf16(av.z, av.w));
        const float4 wv = *reinterpret_cast<const float4*>(
            &W[(size_t)(n0 + row) * E_ + c4 * 4]);
        *reinterpret_cast<uint2*>(bB + swz(row, c4 * 8)) =
            make_uint2(pk_bf16(wv.x, wv.y), pk_bf16(wv.z, wv.w));
    }
    __syncthreads();

    // ---- MFMA: wave w owns quadrant (w>>1, w&1)
    const int l  = t & 63;
    const int w  = t >> 6;
    const int mb = (w >> 1) * 32;
    const int nb = (w & 1) * 32;
    const int lr = l & 15;              // frag row/col within 16
    const int lk = (l >> 4) * 16;       // k-group byte offset (8 bf16)

    f32x4 acc[2][2] = {};

    #pragma unroll
    for (int ks = 0; ks < 8; ++ks) {
        const int kb = ks * 64 + lk;
        const s16x8 a0 = *reinterpret_cast<const s16x8*>(aB + swz(mb + lr,      kb));
        const s16x8 a1 = *reinterpret_cast<const s16x8*>(aB + swz(mb + 16 + lr, kb));
        const s16x8 b0 = *reinterpret_cast<const s16x8*>(bB + swz(nb + lr,      kb));
        const s16x8 b1 = *reinterpret_cast<const s16x8*>(bB + swz(nb + 16 + lr, kb));
        acc[0][0] = __builtin_amdgcn_mfma_f32_16x16x32_bf16(a0, b0, acc[0][0], 0, 0, 0);
        acc[0][1] = __builtin_amdgcn_mfma_f32_16x16x32_bf16(a0, b1, acc[0][1], 0, 0, 0);
        acc[1][0] = __builtin_amdgcn_mfma_f32_16x16x32_bf16(a1, b0, acc[1][0], 0, 0, 0);
        acc[1][1] = __builtin_amdgcn_mfma_f32_16x16x32_bf16(a1, b1, acc[1][1], 0, 0, 0);
    }

    // ---- C write: col = lane&15, row = (lane>>4)*4 + reg  [m89 verified]
    #pragma unroll
    for (int mi = 0; mi < 2; ++mi) {
        #pragma unroll
        for (int ni = 0; ni < 2; ++ni) {
            const int row = m0 + mb + mi * 16 + (l >> 4) * 4;
            const int col = n0 + nb + ni * 16 + lr;
            #pragma unroll
            for (int j = 0; j < 4; ++j)
                C[(size_t)(row + j) * E_ + col] = acc[mi][ni][j];
        }
    }
}

// ---------------------------------------------------------------------------
// Fused attention: one block per (b,i) row. 33-bucket softmax (exact
// reassociation of the reference). rel_emb staged in LDS with padded row
// stride 260 floats (16B-aligned, spreads cross-r b128 reads over banks).
// ---------------------------------------------------------------------------
__global__ __launch_bounds__(256) void attn_kernel(
    const float* __restrict__ ws,          // q | k | v, each ROWS_*E_
    const int*   __restrict__ relations,   // [B,S,S] int32
    const float* __restrict__ rel_emb,     // [33, E]
    float* __restrict__ out)               // [B,S,E]
{
    constexpr int EST = 260;                           // padded row stride
    __shared__ __align__(16) float emb_s[NR_ * EST];   // 34.3 KB
    __shared__ __align__(16) float q_s[E_];
    __shared__ float qr_s[H_][NR_];
    __shared__ float qkd_s[H_];
    __shared__ int   cnt_s[NR_];

    const int t   = threadIdx.x;           // 256 threads
    const int row = blockIdx.x;            // b*S + i
    const float* q = ws;
    const float* k = ws + MATELEMS_;
    const float* v = ws + 2 * MATELEMS_;

    // stage rel_emb: 33 rows x 64 float4 (row-aware for padded stride)
    {
        const float4* src = reinterpret_cast<const float4*>(rel_emb);
        #pragma unroll
        for (int i = t; i < NR_ * 64; i += 256) {
            const int r = i >> 6;
            const int c = i & 63;
            *reinterpret_cast<float4*>(&emb_s[r * EST + c * 4]) = src[r * 64 + c];
        }
    }
    q_s[t] = q[(size_t)row * E_ + t];
    if (t < NR_) cnt_s[t] = 0;
    const float kv = k[(size_t)row * E_ + t];
    __syncthreads();

    const int h = t >> 5;                  // head
    const int d = t & 31;                  // dim within head

    // qk_diag[h] = q_i . k_i (per head) — 32-lane group reduction
    float prod = q_s[t] * kv;
    #pragma unroll
    for (int m = 16; m >= 1; m >>= 1) prod += __shfl_xor(prod, m);
    if (d == 0) qkd_s[h] = prod;

    // histogram of relations[b,i,:]
    {
        const int r0 = relations[(size_t)row * S_ + t];
        const int r1 = relations[(size_t)row * S_ + t + 256];
        atomicAdd(&cnt_s[r0], 1);
        atomicAdd(&cnt_s[r1], 1);
    }

    // qr[h][r] = q_i[hD:(h+1)D] . rel_emb[r, hD:(h+1)D]   (264 tasks, float4)
    for (int tt = t; tt < H_ * NR_; tt += 256) {
        const int hh = tt / NR_;
        const int r  = tt - hh * NR_;
        const float4* e4 = reinterpret_cast<const float4*>(&emb_s[r * EST + hh * D_]);
        const float4* q4 = reinterpret_cast<const float4*>(&q_s[hh * D_]);
        float s = 0.f;
        #pragma unroll
        for (int dd = 0; dd < D_ / 4; ++dd) {
            const float4 qv = q4[dd];
            const float4 ev = e4[dd];
            s += qv.x * ev.x + qv.y * ev.y + qv.z * ev.z + qv.w * ev.w;
        }
        qr_s[hh][r] = s;
    }
    __syncthreads();

    // bucket softmax + output
    const float scale = 0.17677669529663687f;   // 1/sqrt(32)
    const float qkd = qkd_s[h];
    float mmax = -1e30f;
    #pragma unroll
    for (int r = 0; r < NR_; ++r)
        mmax = fmaxf(mmax, qkd + qr_s[h][r]);
    mmax *= scale;

    float denom = 0.f, acc = 0.f;
    #pragma unroll
    for (int r = 0; r < NR_; ++r) {
        const float e = (float)cnt_s[r] * __expf((qkd + qr_s[h][r]) * scale - mmax);
        denom += e;
        acc   += e * emb_s[r * EST + t];   // h*D + d == t
    }
    out[(size_t)row * E_ + t] = v[(size_t)row * E_ + t] + acc / denom;
}

extern "C" void kernel_launch(void* const* d_in, const int* in_sizes, int n_in,
                              void* d_out, int out_size, void* d_ws, size_t ws_size,
                              hipStream_t stream) {
    const float* query     = (const float*)d_in[0];
    const float* key       = (const float*)d_in[1];
    const float* value     = (const float*)d_in[2];
    const int*   relations = (const int*)  d_in[3];
    const float* W_Q       = (const float*)d_in[4];
    const float* W_K       = (const float*)d_in[5];
    const float* W_V       = (const float*)d_in[6];
    const float* rel_emb   = (const float*)d_in[7];
    float* out = (float*)d_out;
    float* ws  = (float*)d_ws;   // q | k | v projections, 3 MB

    dim3 pgrid(ROWS_ / 64, E_ / 64, 3);
    proj_kernel<<<pgrid, 256, 0, stream>>>(query, key, value, W_Q, W_K, W_V, ws);
    attn_kernel<<<ROWS_, 256, 0, stream>>>(ws, relations, rel_emb, out);
}

// Round 4
// 14.663 us; speedup vs baseline: 2.5815x; 1.2973x over previous
//
#include <hip/hip_runtime.h>
#include <math.h>

// Shapes fixed by the problem: B=2, S=512, E=256, H=8, D=32, 33 relation buckets.
namespace {
constexpr int E_  = 256;
constexpr int H_  = 8;
constexpr int D_  = 32;
constexpr int S_  = 512;
constexpr int B_  = 2;
constexpr int NR_ = 33;
constexpr int RC_ = 32;                 // rows per block
constexpr int ROWS_ = B_ * S_;          // 1024
}

using f32x4 = __attribute__((ext_vector_type(4))) float;
using s16x8 = __attribute__((ext_vector_type(8))) short;

// fp32 -> bf16 round-to-nearest-even, packed pair into one u32
__device__ inline unsigned pk_bf16(float a, float b) {
    unsigned ua = __float_as_uint(a); ua += 0x7FFFu + ((ua >> 16) & 1u);
    unsigned ub = __float_as_uint(b); ub += 0x7FFFu + ((ub >> 16) & 1u);
    return (ua >> 16) | (ub & 0xFFFF0000u);
}

// XOR-swizzled byte offset within a [32 rows][128 B] bf16 k-tile:
// rows 0-7 spread over all 32 banks for the 16-row fragment reads (2-way = free).
__device__ inline int swz(int row, int kbyte) {
    return row * 128 + (kbyte ^ ((row & 7) << 4));
}

// ---------------------------------------------------------------------------
// Fully fused kernel. Block (chunk, h) owns rows [chunk*32, +32) and head h:
//  - projects q/k/v head-slices [32x32] via bf16 MFMA (W rows h*32..h*32+31),
//    K=256 processed in 4 k-tiles of 64, register-prefetched, swizzled LDS
//  - per-row relation histogram (LDS atomics)
//  - 33-bucket softmax (exact reassociation of the reference S x S softmax)
//  - out[row, h*32+d] = v + sum_r w_r * rel_emb[r, h*32+d]
// grid = (32, 8), 256 threads. LDS ~51 KB.
// ---------------------------------------------------------------------------
__global__ __launch_bounds__(256) void fused_kernel(
    const float* __restrict__ q_in, const float* __restrict__ k_in,
    const float* __restrict__ v_in,
    const float* __restrict__ WQ, const float* __restrict__ WK,
    const float* __restrict__ WV,
    const int*   __restrict__ relations,   // [B,S,S] int32
    const float* __restrict__ rel_emb,     // [33, E]
    float* __restrict__ out)               // [B,S,E]
{
    __shared__ __align__(16) char  tiles[6][RC_ * 128];   // 24 KB bf16 k-tiles
    __shared__ __align__(16) float qkv_s[3][RC_][36];     // 13.8 KB (stride 36: 16B-aligned rows)
    __shared__ __align__(16) float emb_s[NR_ * D_];       // 4.2 KB head-slice of rel_emb
    __shared__ float qr_s[RC_ * NR_];                     // 4.2 KB (reused as weights)
    __shared__ int   cnt_s[RC_ * NR_];                    // 4.2 KB
    __shared__ float qkd_s[RC_];

    const int t  = threadIdx.x;
    const int r0 = blockIdx.x * RC_;       // row base
    const int h  = blockIdx.y;
    const int c0 = h * D_;                 // col base (head slice)

    float4 pre[12];                        // staged k-tile (register prefetch)

    auto issue_loads = [&](int kt) {
        #pragma unroll
        for (int j = 0; j < 12; ++j) {
            const int tau = j >> 1;                    // compile-time after unroll
            const int idx = t + 256 * (j & 1);         // 0..511 within tile
            const int row = idx >> 4;
            const int cf  = (idx & 15) * 4;            // float col within 64
            const float* src = (tau == 0) ? q_in : (tau == 1) ? k_in
                             : (tau == 2) ? v_in : (tau == 3) ? WQ
                             : (tau == 4) ? WK   : WV;
            const int rb = (tau < 3) ? r0 : c0;
            pre[j] = *reinterpret_cast<const float4*>(
                &src[(size_t)(rb + row) * E_ + kt * 64 + cf]);
        }
    };
    auto write_tiles = [&]() {
        #pragma unroll
        for (int j = 0; j < 12; ++j) {
            const int tau = j >> 1;
            const int idx = t + 256 * (j & 1);
            const int row = idx >> 4;
            const int cb  = (idx & 15) * 8;            // byte col (8 B = 4 bf16)
            *reinterpret_cast<uint2*>(tiles[tau] + swz(row, cb)) =
                make_uint2(pk_bf16(pre[j].x, pre[j].y), pk_bf16(pre[j].z, pre[j].w));
        }
    };

    // ---- init: zero histogram, stage emb head-slice, issue k-tile 0 loads
    for (int i = t; i < RC_ * NR_; i += 256) cnt_s[i] = 0;
    for (int g = t; g < NR_ * D_ / 4; g += 256) {      // 264 float4
        const int r = g >> 3, d4 = (g & 7) * 4;
        *reinterpret_cast<float4*>(&emb_s[r * D_ + d4]) =
            *reinterpret_cast<const float4*>(&rel_emb[(size_t)r * E_ + c0 + d4]);
    }
    issue_loads(0);
    __syncthreads();                                   // cnt zeroed

    // ---- histogram of relations for owned rows (loads overlap k-tile-0 latency)
    {
        const int hrow = t >> 3, hl = t & 7;
        const int* relrow = relations + (size_t)(r0 + hrow) * S_;
        #pragma unroll
        for (int i = 0; i < 16; ++i) {
            const int4 rv = *reinterpret_cast<const int4*>(&relrow[hl * 4 + i * 32]);
            atomicAdd(&cnt_s[hrow * NR_ + rv.x], 1);
            atomicAdd(&cnt_s[hrow * NR_ + rv.y], 1);
            atomicAdd(&cnt_s[hrow * NR_ + rv.z], 1);
            atomicAdd(&cnt_s[hrow * NR_ + rv.w], 1);
        }
    }

    // ---- projection GEMMs: wave w owns 16x16 quadrant (w>>1, w&1) of all 3
    const int l  = t & 63;
    const int w  = t >> 6;
    const int mi = (w >> 1) * 16;
    const int ni = (w & 1) * 16;
    const int lr = l & 15;
    const int lk = (l >> 4) * 16;          // byte offset of 8-bf16 k-group

    f32x4 accq = {}, acck = {}, accv = {};

    for (int kt = 0; kt < 4; ++kt) {
        write_tiles();
        __syncthreads();
        if (kt < 3) issue_loads(kt + 1);   // in-flight across MFMA + barrier
        #pragma unroll
        for (int s = 0; s < 2; ++s) {
            const int kb = s * 64 + lk;
            const s16x8 aq = *reinterpret_cast<const s16x8*>(tiles[0] + swz(mi + lr, kb));
            const s16x8 ak = *reinterpret_cast<const s16x8*>(tiles[1] + swz(mi + lr, kb));
            const s16x8 av = *reinterpret_cast<const s16x8*>(tiles[2] + swz(mi + lr, kb));
            const s16x8 bq = *reinterpret_cast<const s16x8*>(tiles[3] + swz(ni + lr, kb));
            const s16x8 bk = *reinterpret_cast<const s16x8*>(tiles[4] + swz(ni + lr, kb));
            const s16x8 bv = *reinterpret_cast<const s16x8*>(tiles[5] + swz(ni + lr, kb));
            accq = __builtin_amdgcn_mfma_f32_16x16x32_bf16(aq, bq, accq, 0, 0, 0);
            acck = __builtin_amdgcn_mfma_f32_16x16x32_bf16(ak, bk, acck, 0, 0, 0);
            accv = __builtin_amdgcn_mfma_f32_16x16x32_bf16(av, bv, accv, 0, 0, 0);
        }
        __syncthreads();
    }

    // ---- write q/k/v slices to LDS (C layout: col=lane&15, row=(lane>>4)*4+j)
    #pragma unroll
    for (int j = 0; j < 4; ++j) {
        const int row = mi + (l >> 4) * 4 + j;
        const int col = ni + lr;
        qkv_s[0][row][col] = accq[j];
        qkv_s[1][row][col] = acck[j];
        qkv_s[2][row][col] = accv[j];
    }
    __syncthreads();

    const int erow = t >> 3, el = t & 7;

    // ---- qk_diag (per-row, per-head dot over 32 dims)
    {
        const f32x4 qv = *reinterpret_cast<const f32x4*>(&qkv_s[0][erow][el * 4]);
        const f32x4 kv = *reinterpret_cast<const f32x4*>(&qkv_s[1][erow][el * 4]);
        float p = qv[0]*kv[0] + qv[1]*kv[1] + qv[2]*kv[2] + qv[3]*kv[3];
        p += __shfl_xor(p, 1); p += __shfl_xor(p, 2); p += __shfl_xor(p, 4);
        if (el == 0) qkd_s[erow] = p;
    }

    // ---- qr[row][r] = q_row . emb_r (1056 dot-32 tasks)
    for (int g = t; g < RC_ * NR_; g += 256) {
        const int row = g & 31, r = g >> 5;
        const f32x4* qp = reinterpret_cast<const f32x4*>(&qkv_s[0][row][0]);
        const f32x4* ep = reinterpret_cast<const f32x4*>(&emb_s[r * D_]);
        float s = 0.f;
        #pragma unroll
        for (int u = 0; u < 8; ++u) {
            const f32x4 a = qp[u], b = ep[u];
            s += a[0]*b[0] + a[1]*b[1] + a[2]*b[2] + a[3]*b[3];
        }
        qr_s[row * NR_ + r] = s;
    }
    __syncthreads();

    // ---- per-row bucket softmax -> weights (in place over qr_s)
    {
        constexpr float scale = 0.17677669529663687f;  // 1/sqrt(32)
        const float qkd = qkd_s[erow];
        float z[5], m = -1e30f;
        #pragma unroll
        for (int u = 0; u < 5; ++u) {
            const int r = el + 8 * u;
            z[u] = (r < NR_) ? (qkd + qr_s[erow * NR_ + r]) * scale : -1e30f;
            m = fmaxf(m, z[u]);
        }
        m = fmaxf(m, __shfl_xor(m, 1));
        m = fmaxf(m, __shfl_xor(m, 2));
        m = fmaxf(m, __shfl_xor(m, 4));
        float e[5], sum = 0.f;
        #pragma unroll
        for (int u = 0; u < 5; ++u) {
            const int r = el + 8 * u;
            e[u] = (r < NR_) ? (float)cnt_s[erow * NR_ + r] * __expf(z[u] - m) : 0.f;
            sum += e[u];
        }
        sum += __shfl_xor(sum, 1);
        sum += __shfl_xor(sum, 2);
        sum += __shfl_xor(sum, 4);
        const float inv = 1.0f / sum;
        #pragma unroll
        for (int u = 0; u < 5; ++u) {
            const int r = el + 8 * u;
            if (r < NR_) qr_s[erow * NR_ + r] = e[u] * inv;
        }
    }
    __syncthreads();

    // ---- output: out[row, c0+d] = v + sum_r w_r * emb_r[d]
    {
        const int d0 = el * 4;
        f32x4 acc = *reinterpret_cast<const f32x4*>(&qkv_s[2][erow][d0]);
        #pragma unroll
        for (int r = 0; r < NR_; ++r) {
            const float wv = qr_s[erow * NR_ + r];
            const f32x4 ev = *reinterpret_cast<const f32x4*>(&emb_s[r * D_ + d0]);
            acc[0] += wv * ev[0]; acc[1] += wv * ev[1];
            acc[2] += wv * ev[2]; acc[3] += wv * ev[3];
        }
        *reinterpret_cast<f32x4*>(&out[(size_t)(r0 + erow) * E_ + c0 + d0]) = acc;
    }
}

extern "C" void kernel_launch(void* const* d_in, const int* in_sizes, int n_in,
                              void* d_out, int out_size, void* d_ws, size_t ws_size,
                              hipStream_t stream) {
    const float* query     = (const float*)d_in[0];
    const float* key       = (const float*)d_in[1];
    const float* value     = (const float*)d_in[2];
    const int*   relations = (const int*)  d_in[3];
    const float* W_Q       = (const float*)d_in[4];
    const float* W_K       = (const float*)d_in[5];
    const float* W_V       = (const float*)d_in[6];
    const float* rel_emb   = (const float*)d_in[7];
    float* out = (float*)d_out;

    dim3 grid(ROWS_ / RC_, H_);            // (32, 8) = 256 blocks, one per CU
    fused_kernel<<<grid, 256, 0, stream>>>(query, key, value, W_Q, W_K, W_V,
                                           relations, rel_emb, out);
}

// Round 5
// 12.495 us; speedup vs baseline: 3.0294x; 1.1735x over previous
//
#include <hip/hip_runtime.h>
#include <math.h>

// Shapes fixed by the problem: B=2, S=512, E=256, H=8, D=32, 33 relation buckets.
// Key algebra: scores = (qk_diag[i] + q_i.r_ij)*scale with qk_diag j-independent
// -> cancels EXACTLY in softmax_j  -> key/W_K are dead; alpha depends only on
// the 33 relation buckets -> 33-bucket softmax (exact reassociation).
namespace {
constexpr int E_  = 256;
constexpr int H_  = 8;
constexpr int D_  = 32;
constexpr int S_  = 512;
constexpr int NR_ = 33;
constexpr int RC_ = 32;                 // rows per block
constexpr int ROWS_ = 1024;
}

using f32x4 = __attribute__((ext_vector_type(4))) float;
using s16x8 = __attribute__((ext_vector_type(8))) short;

// fp32 -> bf16 round-to-nearest-even, packed pair into one u32
__device__ inline unsigned pk_bf16(float a, float b) {
    unsigned ua = __float_as_uint(a); ua += 0x7FFFu + ((ua >> 16) & 1u);
    unsigned ub = __float_as_uint(b); ub += 0x7FFFu + ((ub >> 16) & 1u);
    return (ua >> 16) | (ub & 0xFFFF0000u);
}
__device__ inline unsigned short bf16_1(float a) {
    unsigned ua = __float_as_uint(a); ua += 0x7FFFu + ((ua >> 16) & 1u);
    return (unsigned short)(ua >> 16);
}

// XOR-swizzled byte offset within a [32 rows][128 B] bf16 k-tile.
__device__ inline int swz(int row, int kbyte) {
    return row * 128 + (kbyte ^ ((row & 7) << 4));
}

// Raw barrier that drains LDS ops only — prefetched global loads stay in
// flight across it (T3/T4; __syncthreads would drain vmcnt(0) too).
__device__ inline void bar_lgkm() {
    asm volatile("s_waitcnt lgkmcnt(0)" ::: "memory");
    __builtin_amdgcn_s_barrier();
    __builtin_amdgcn_sched_barrier(0);
}

// ---------------------------------------------------------------------------
// One fully fused kernel. Block (chunk,h): rows [chunk*32,+32), head h.
//  - q,v head-slice projections [32x32] via bf16 MFMA (K=256, 4 k-tiles,
//    2-deep register prefetch surviving the lgkm-only barriers)
//  - per-row relation histogram (LDS atomics, spread across GEMM iters)
//  - qr[row][bucket] via 6 more MFMAs (32x48 x K=32)
//  - 33-bucket softmax, out = v + sum_r w_r * rel_emb[r]
// grid=(32,8)=256 blocks (1/CU; same-chunk blocks share an XCD), 256 thr.
// ---------------------------------------------------------------------------
__global__ __launch_bounds__(256) void fused_kernel(
    const float* __restrict__ q_in, const float* __restrict__ v_in,
    const float* __restrict__ WQ,  const float* __restrict__ WV,
    const int*   __restrict__ relations,   // [B,S,S] int32
    const float* __restrict__ rel_emb,     // [33, E]
    float* __restrict__ out)               // [B,S,E]
{
    __shared__ __align__(16) char  tiles[4][RC_ * 128];       // 16 KB q|v|WQ|WV
    __shared__ __align__(16) float v_s[RC_][36];              // 4.6 KB fp32 v
    __shared__ __align__(16) unsigned short qbf_s[RC_ * 32];  // 2 KB bf16 q [row][k]
    __shared__ __align__(16) float emb_s[NR_ * D_];           // 4.2 KB fp32 emb slice
    __shared__ __align__(16) unsigned short ebf_s[48 * 32];   // 3 KB bf16 emb (padded)
    __shared__ float qr_s[RC_][52];                           // 6.6 KB
    __shared__ int   cnt_s[RC_ * NR_];                        // 4.2 KB

    const int t  = threadIdx.x;
    const int r0 = blockIdx.x * RC_;
    const int h  = blockIdx.y;
    const int c0 = h * D_;

    float4 pre[16];                        // 2 k-tiles in flight
    auto issue = [&](int kt, int buf) {
        #pragma unroll
        for (int j = 0; j < 8; ++j) {
            const int tau = j >> 1;                  // 0=q 1=v 2=WQ 3=WV
            const int idx = t + 256 * (j & 1);
            const int row = idx >> 4;
            const int cf  = (idx & 15) * 4;
            const float* src = (tau == 0) ? q_in : (tau == 1) ? v_in
                             : (tau == 2) ? WQ   : WV;
            const int rb = (tau < 2) ? r0 : c0;
            pre[buf * 8 + j] = *reinterpret_cast<const float4*>(
                &src[(size_t)(rb + row) * E_ + kt * 64 + cf]);
        }
    };
    auto wtiles = [&](int buf) {
        #pragma unroll
        for (int j = 0; j < 8; ++j) {
            const int tau = j >> 1;
            const int idx = t + 256 * (j & 1);
            const int row = idx >> 4;
            const int cb  = (idx & 15) * 8;
            const float4 p = pre[buf * 8 + j];
            *reinterpret_cast<uint2*>(tiles[tau] + swz(row, cb)) =
                make_uint2(pk_bf16(p.x, p.y), pk_bf16(p.z, p.w));
        }
    };

    // ---- init: issue tiles 0,1 + all relation loads, then LDS init
    issue(0, 0);
    issue(1, 1);
    const int hrow = t >> 3, hl = t & 7;
    int4 rel[16];
    {
        const int* relrow = relations + (size_t)(r0 + hrow) * S_;
        #pragma unroll
        for (int i = 0; i < 16; ++i)
            rel[i] = *reinterpret_cast<const int4*>(&relrow[hl * 4 + i * 32]);
    }
    for (int i = t; i < RC_ * NR_; i += 256) cnt_s[i] = 0;
    for (int g = t; g < NR_ * D_ / 4; g += 256) {       // 264 float4
        const int r = g >> 3, d4 = (g & 7) * 4;
        const float4 ev = *reinterpret_cast<const float4*>(
            &rel_emb[(size_t)r * E_ + c0 + d4]);
        *reinterpret_cast<float4*>(&emb_s[r * D_ + d4]) = ev;
        *reinterpret_cast<uint2*>(&ebf_s[r * 32 + d4]) =
            make_uint2(pk_bf16(ev.x, ev.y), pk_bf16(ev.z, ev.w));
    }
    for (int i = t; i < (48 - NR_) * 32 / 2; i += 256)  // zero bf16 pad rows
        reinterpret_cast<unsigned*>(ebf_s + NR_ * 32)[i] = 0;
    bar_lgkm();

    // ---- projection GEMMs: wave w owns 16x16 quadrant (w>>1, w&1)
    const int l  = t & 63;
    const int w  = t >> 6;
    const int mi = (w >> 1) * 16;
    const int ni = (w & 1) * 16;
    const int lr = l & 15;
    const int lk = (l >> 4) * 16;          // byte offset of 8-bf16 k-group

    f32x4 accq = {}, accv = {};

    #pragma unroll
    for (int kt = 0; kt < 4; ++kt) {
        wtiles(kt & 1);
        if (kt < 2) issue(kt + 2, kt & 1);
        bar_lgkm();
        #pragma unroll
        for (int s = 0; s < 2; ++s) {
            const int kb = s * 64 + lk;
            const s16x8 aq = *reinterpret_cast<const s16x8*>(tiles[0] + swz(mi + lr, kb));
            const s16x8 av = *reinterpret_cast<const s16x8*>(tiles[1] + swz(mi + lr, kb));
            const s16x8 bq = *reinterpret_cast<const s16x8*>(tiles[2] + swz(ni + lr, kb));
            const s16x8 bv = *reinterpret_cast<const s16x8*>(tiles[3] + swz(ni + lr, kb));
            accq = __builtin_amdgcn_mfma_f32_16x16x32_bf16(aq, bq, accq, 0, 0, 0);
            accv = __builtin_amdgcn_mfma_f32_16x16x32_bf16(av, bv, accv, 0, 0, 0);
        }
        // histogram chunk kt (rel loads long landed; LDS region disjoint)
        #pragma unroll
        for (int i = 0; i < 4; ++i) {
            const int4 rv = rel[kt * 4 + i];
            atomicAdd(&cnt_s[hrow * NR_ + rv.x], 1);
            atomicAdd(&cnt_s[hrow * NR_ + rv.y], 1);
            atomicAdd(&cnt_s[hrow * NR_ + rv.z], 1);
            atomicAdd(&cnt_s[hrow * NR_ + rv.w], 1);
        }
        bar_lgkm();
    }

    // ---- write projections: v fp32 (for output), q bf16 (A-frag layout)
    #pragma unroll
    for (int j = 0; j < 4; ++j) {
        const int row = mi + (l >> 4) * 4 + j;      // C: col=lane&15, row=(lane>>4)*4+j
        const int col = ni + lr;
        v_s[row][col] = accv[j];
        qbf_s[row * 32 + col] = bf16_1(accq[j]);
    }
    bar_lgkm();

    // ---- qr[row][r] = q_row . emb_r  via MFMA (32x48, K=32 in one shot)
    {
        const int kq = (l >> 4) * 8;               // bf16 k offset
        const int Hh = w >> 1;                     // row half
        const int G  = w & 1;                      // bucket group (waves 0,2 also do G=2)
        const s16x8 afr = *reinterpret_cast<const s16x8*>(&qbf_s[(Hh * 16 + lr) * 32 + kq]);
        const s16x8 bfr = *reinterpret_cast<const s16x8*>(&ebf_s[(G  * 16 + lr) * 32 + kq]);
        f32x4 r1 = {};
        r1 = __builtin_amdgcn_mfma_f32_16x16x32_bf16(afr, bfr, r1, 0, 0, 0);
        #pragma unroll
        for (int j = 0; j < 4; ++j)
            qr_s[Hh * 16 + (l >> 4) * 4 + j][G * 16 + lr] = r1[j];
        if ((w & 1) == 0) {
            const s16x8 bf2 = *reinterpret_cast<const s16x8*>(&ebf_s[(32 + lr) * 32 + kq]);
            f32x4 r2 = {};
            r2 = __builtin_amdgcn_mfma_f32_16x16x32_bf16(afr, bf2, r2, 0, 0, 0);
            #pragma unroll
            for (int j = 0; j < 4; ++j)
                qr_s[Hh * 16 + (l >> 4) * 4 + j][32 + lr] = r2[j];
        }
    }
    bar_lgkm();

    // ---- per-row bucket softmax (8 lanes/row; qk_diag cancels, omitted)
    const int erow = t >> 3, el = t & 7;
    {
        constexpr float scale = 0.17677669529663687f;  // 1/sqrt(32)
        float z[5], m = -1e30f;
        #pragma unroll
        for (int u = 0; u < 5; ++u) {
            const int r = el + 8 * u;
            z[u] = (r < NR_) ? qr_s[erow][r] * scale : -1e30f;
            m = fmaxf(m, z[u]);
        }
        m = fmaxf(m, __shfl_xor(m, 1));
        m = fmaxf(m, __shfl_xor(m, 2));
        m = fmaxf(m, __shfl_xor(m, 4));
        float e[5], sum = 0.f;
        #pragma unroll
        for (int u = 0; u < 5; ++u) {
            const int r = el + 8 * u;
            e[u] = (r < NR_) ? (float)cnt_s[erow * NR_ + r] * __expf(z[u] - m) : 0.f;
            sum += e[u];
        }
        sum += __shfl_xor(sum, 1);
        sum += __shfl_xor(sum, 2);
        sum += __shfl_xor(sum, 4);
        const float inv = 1.0f / sum;
        #pragma unroll
        for (int u = 0; u < 5; ++u) {
            const int r = el + 8 * u;
            if (r < NR_) qr_s[erow][r] = e[u] * inv;
        }
    }
    bar_lgkm();

    // ---- output: out[row, c0+d] = v + sum_r w_r * emb_r[d]
    {
        const int d0 = el * 4;
        f32x4 acc = *reinterpret_cast<const f32x4*>(&v_s[erow][d0]);
        #pragma unroll
        for (int r = 0; r < NR_; ++r) {
            const float wv = qr_s[erow][r];
            const f32x4 ev = *reinterpret_cast<const f32x4*>(&emb_s[r * D_ + d0]);
            acc[0] += wv * ev[0]; acc[1] += wv * ev[1];
            acc[2] += wv * ev[2]; acc[3] += wv * ev[3];
        }
        *reinterpret_cast<f32x4*>(&out[(size_t)(r0 + erow) * E_ + c0 + d0]) = acc;
    }
}

extern "C" void kernel_launch(void* const* d_in, const int* in_sizes, int n_in,
                              void* d_out, int out_size, void* d_ws, size_t ws_size,
                              hipStream_t stream) {
    const float* query     = (const float*)d_in[0];
    const float* value     = (const float*)d_in[2];
    const int*   relations = (const int*)  d_in[3];
    const float* W_Q       = (const float*)d_in[4];
    const float* W_V       = (const float*)d_in[6];
    const float* rel_emb   = (const float*)d_in[7];
    float* out = (float*)d_out;

    dim3 grid(ROWS_ / RC_, H_);            // (32, 8) = 256 blocks, one per CU
    fused_kernel<<<grid, 256, 0, stream>>>(query, value, W_Q, W_V,
                                           relations, rel_emb, out);
}